// Round 2
// baseline (1182.290 us; speedup 1.0000x reference)
//
#include <hip/hip_runtime.h>
#include <cstdint>
#include <cstddef>

// Experts MoE FFN: y = gelu(x @ w1^T + b1) @ w2^T + b2, 8 experts.
// R3: attack latency exposure (both GEMMs ride a 4.2 TB/s staged-read delivery
// limit at 1 block/CU; m97-structure sustained 13.4 TB/s on this chip).
//   - A triple-buffered, B double-buffered: LDS = 96+64 = 160 KiB (HW max).
//   - Per tile kt: P1/P2 stage A(kt+2) -> buf (kt+2)%3 (slack 6-7 phases),
//     P3/P4 stage B(kt+2) -> buf kt%2 (slack 4-5), gate vmcnt(8) at P4
//     (drains exactly the previous tile's 8 loads; peak 16 in flight).
//   - gelu via A&S 7.1.26 erf (|eps|<=1.5e-7, no accuracy risk) -- ~15 VALU
//     vs ~30 for libm erff; GEMM1's epilogue is 128 gelu/thread.
//   - granule swizzle slot = kchunk ^ (row&7) on BOTH pre-swizzled global src
//     and ds_read addr (bank-conflict-free, counter-verified 0).

typedef __bf16 bf16;
typedef __attribute__((ext_vector_type(8))) __bf16 bf16x8;
typedef __attribute__((ext_vector_type(4))) __bf16 bf16x4;
typedef __attribute__((ext_vector_type(4))) float floatx4;

#define FENCE() asm volatile("" ::: "memory")
#define BAR() do { FENCE(); __builtin_amdgcn_s_barrier(); FENCE(); } while (0)
#define VMCNT(n) asm volatile("s_waitcnt vmcnt(" #n ")" ::: "memory")
#define MFMA16(a, b, c) __builtin_amdgcn_mfma_f32_16x16x32_bf16((a), (b), (c), 0, 0, 0)

// Async global->LDS DMA, 16B/lane. LDS dest is wave-uniform base + lane*16,
// so dest granule indices must be lane-contiguous (g = base + tid is).
__device__ __forceinline__ void async_copy16(void* lds_ptr, const void* g_ptr) {
  __builtin_amdgcn_global_load_lds(
      (const __attribute__((address_space(1))) uint32_t*)g_ptr,
      (__attribute__((address_space(3))) uint32_t*)lds_ptr,
      16, 0, 0);
}

// Exact gelu: 0.5*x*(1+erf(x/sqrt2)), erf by Abramowitz-Stegun 7.1.26
// (|eps| <= 1.5e-7 -> bit-identical vs erff at bf16/fp32 output scale).
__device__ __forceinline__ float gelu_fast(float x) {
  const float ax = fabsf(x);
  const float az = ax * 0.70710678118654752f;
  const float t = __fdividef(1.0f, fmaf(az, 0.3275911f, 1.0f));
  const float e = __expf(-az * az);
  float p = fmaf(t, 1.061405429f, -1.453152027f);
  p = fmaf(t, p, 1.421413741f);
  p = fmaf(t, p, -0.284496736f);
  p = fmaf(t, p, 0.254829592f);
  const float erf_abs = fmaf(-(p * t), e, 1.0f);  // erf(|z|)
  return 0.5f * (x + ax * erf_abs);               // handles both signs
}

__global__ __launch_bounds__(256) void cvt_f32_to_bf16(
    const float4* __restrict__ src, bf16x4* __restrict__ dst, int n4) {
  int i = blockIdx.x * 256 + threadIdx.x;
  if (i < n4) {
    float4 v = src[i];
    bf16x4 o = {(bf16)v.x, (bf16)v.y, (bf16)v.z, (bf16)v.w};
    dst[i] = o;
  }
}

// Grouped GEMM, A row-major [32768,K], B per-expert [N,K] row-major (B^T path).
// Out[m][n] = sum_k A[m][k]*B[e][n][k] + bias[e][n]; optional exact gelu.
// 256x256 tile, BK=64, 512 thr = 8 waves (2M x 4N), per-wave 128x64 out.
template <int KDIM, int NDIM, bool GELU, typename OutT>
__global__ __launch_bounds__(512, 2) void gemm256_8ph(
    const bf16* __restrict__ A,      // [32768, KDIM]
    const bf16* __restrict__ Bw,     // [8, NDIM, KDIM]
    const float* __restrict__ bias,  // [8, NDIM]
    OutT* __restrict__ Out) {        // [32768, NDIM]
  constexpr int NT = KDIM / 64;          // K-tiles
  constexpr int NB = NDIM / 256;         // n-blocks
  constexpr int NWG = (32768 / 256) * NB;

  // A: 3 bufs x [2 half x 1024 granules]; B: 2 bufs x [2 half x 1024].
  // granule (r,c): holds k-chunk c ^ (r&7). 96 KiB + 64 KiB = 160 KiB (max).
  __shared__ bf16x8 ldsA[6144];
  __shared__ bf16x8 ldsB[4096];

  // XCD-aware swizzle (NWG divisible by 8 -> bijective), n-fastest inside.
  const int wgid = ((int)blockIdx.x & 7) * (NWG / 8) + ((int)blockIdx.x >> 3);
  const int n_blk = wgid % NB;
  const int m_blk = wgid / NB;
  const int e = (m_blk >> 2) & 7;        // 4 row-blocks per 1024-token chunk

  const int tid = threadIdx.x;
  const int lane = tid & 63;
  const int wid = tid >> 6;
  const int wm = wid >> 2;               // 0..1 -> rows wm*128..+127
  const int wn = wid & 3;                // 0..3 -> cols wn*64..+63
  const int lo16 = lane & 15;
  const int q = lane >> 4;

  const bf16* Ab = A + (size_t)m_blk * 256 * KDIM;
  const bf16* Bb = Bw + (size_t)e * NDIM * KDIM + (size_t)n_blk * 256 * KDIM;

  // Staging: thread stages granules (i*512 + tid), i=0,1 per half-tile.
  // row = h*128 + i*64 + (tid>>3); src k-chunk pre-swizzled by row&7.
  const int srow = tid >> 3;
  const int skoff = ((tid & 7) ^ (srow & 7)) * 8;

  // ds_read swizzled slots: k-chunk kk*4+q at row (..+lo16).
  const int sl0 = q ^ (lo16 & 7);
  const int sl1 = (4 + q) ^ (lo16 & 7);
  const int aoff = wm * 1024 + lo16 * 8;
  const int boff = wn * 512 + lo16 * 8;

  floatx4 acc[8][4];
#pragma unroll
  for (int i = 0; i < 8; ++i)
#pragma unroll
    for (int j = 0; j < 4; ++j) acc[i][j] = (floatx4)(0.0f);

  bf16x8 afr[4][2];  // current A half-quadrant (reloaded at phase 3)
  bf16x8 bfr[4][2];  // all 4 n-frags kept live across the K-tile

#define STAGE_A(buf, h, kt_) do {                                              \
    const bf16* s_ = Ab + (size_t)((h) * 128 + srow) * KDIM + ((kt_)*64 + skoff); \
    bf16x8* d_ = &ldsA[(buf) * 2048 + (h) * 1024 + tid];                       \
    async_copy16(d_, s_);                                                      \
    async_copy16(d_ + 512, s_ + (size_t)64 * KDIM);                            \
  } while (0)
#define STAGE_B(buf, h, kt_) do {                                              \
    const bf16* s_ = Bb + (size_t)((h) * 128 + srow) * KDIM + ((kt_)*64 + skoff); \
    bf16x8* d_ = &ldsB[(buf) * 2048 + (h) * 1024 + tid];                       \
    async_copy16(d_, s_);                                                      \
    async_copy16(d_ + 512, s_ + (size_t)64 * KDIM);                            \
  } while (0)

  // Prologue: A(0),B(0) then A(1),B(1). vmcnt(8) -> tile0 landed, tile1 flies.
  STAGE_A(0, 0, 0); STAGE_A(0, 1, 0);
  STAGE_B(0, 0, 0); STAGE_B(0, 1, 0);
  STAGE_A(1, 0, 1); STAGE_A(1, 1, 1);
  STAGE_B(1, 0, 1); STAGE_B(1, 1, 1);
  VMCNT(8);
  BAR();

  // Steady state per tile kt (read A-buf kt%3, B-buf kt&1):
  //   P1: stage A(kt+2)^lo -> (kt+2)%3   [that buf's A(kt-1) read ended P3 of kt-1]
  //   P2: stage A(kt+2)^hi
  //   P3: stage B(kt+2)^lo -> kt&1       [this buf's B reads ended P2]
  //   P4: stage B(kt+2)^hi, vmcnt(8)     [drains tile kt-1's 8 = A(kt+1)+B(kt+1)]
  // Min drain slack: 4 phases (B^hi); A gets 6-7. Peak 16 loads in flight.
  int ar = 0;  // kt % 3
  int as = 2;  // (kt+2) % 3
  for (int kt = 0; kt < NT; ++kt) {
    const int bb = kt & 1;
    const int abase = ar * 2048 + aoff;
    const int bbase = bb * 2048 + boff;
    const int kN = (kt + 2 < NT) ? kt + 2 : NT - 1;  // clamp: dead-slot restage
                                                     // keeps vmcnt counts uniform
    // ---- phase 1: quadrant (mh0, nh0); 12 ds_reads
#pragma unroll
    for (int i = 0; i < 4; ++i) {
      afr[i][0] = ldsA[abase + i * 128 + sl0];
      afr[i][1] = ldsA[abase + i * 128 + sl1];
    }
#pragma unroll
    for (int j = 0; j < 2; ++j) {
      bfr[j][0] = ldsB[bbase + j * 128 + sl0];
      bfr[j][1] = ldsB[bbase + j * 128 + sl1];
    }
    STAGE_A(as, 0, kN);
    BAR();
    __builtin_amdgcn_s_setprio(1);
#pragma unroll
    for (int i = 0; i < 4; ++i)
#pragma unroll
      for (int j = 0; j < 2; ++j) {
        acc[i][j] = MFMA16(afr[i][0], bfr[j][0], acc[i][j]);
        acc[i][j] = MFMA16(afr[i][1], bfr[j][1], acc[i][j]);
      }
    __builtin_amdgcn_s_setprio(0);
    BAR();

    // ---- phase 2: quadrant (mh0, nh1); 4 ds_reads
#pragma unroll
    for (int j = 2; j < 4; ++j) {
      bfr[j][0] = ldsB[bbase + j * 128 + sl0];
      bfr[j][1] = ldsB[bbase + j * 128 + sl1];
    }
    STAGE_A(as, 1, kN);
    BAR();
    __builtin_amdgcn_s_setprio(1);
#pragma unroll
    for (int i = 0; i < 4; ++i)
#pragma unroll
      for (int j = 2; j < 4; ++j) {
        acc[i][j] = MFMA16(afr[i][0], bfr[j][0], acc[i][j]);
        acc[i][j] = MFMA16(afr[i][1], bfr[j][1], acc[i][j]);
      }
    __builtin_amdgcn_s_setprio(0);
    BAR();

    // ---- phase 3: quadrant (mh1, nh0); 8 ds_reads (afr rows +64)
#pragma unroll
    for (int i = 0; i < 4; ++i) {
      afr[i][0] = ldsA[abase + 512 + i * 128 + sl0];
      afr[i][1] = ldsA[abase + 512 + i * 128 + sl1];
    }
    STAGE_B(bb, 0, kN);
    BAR();
    __builtin_amdgcn_s_setprio(1);
#pragma unroll
    for (int i = 0; i < 4; ++i)
#pragma unroll
      for (int j = 0; j < 2; ++j) {
        acc[4 + i][j] = MFMA16(afr[i][0], bfr[j][0], acc[4 + i][j]);
        acc[4 + i][j] = MFMA16(afr[i][1], bfr[j][1], acc[4 + i][j]);
      }
    __builtin_amdgcn_s_setprio(0);
    BAR();

    // ---- phase 4: quadrant (mh1, nh1); 0 ds_reads; counted vmcnt
    STAGE_B(bb, 1, kN);
    BAR();
    __builtin_amdgcn_s_setprio(1);
#pragma unroll
    for (int i = 0; i < 4; ++i)
#pragma unroll
      for (int j = 2; j < 4; ++j) {
        acc[4 + i][j] = MFMA16(afr[i][0], bfr[j][0], acc[4 + i][j]);
        acc[4 + i][j] = MFMA16(afr[i][1], bfr[j][1], acc[4 + i][j]);
      }
    __builtin_amdgcn_s_setprio(0);
    VMCNT(8);  // drain previous tile's stages only; keep 8 in flight
    BAR();

    ar = (ar == 2) ? 0 : ar + 1;
    as = (as == 2) ? 0 : as + 1;
  }
  VMCNT(0);  // drain tail restages before LDS goes out of scope

  // Epilogue. C/D layout: col = lane&15, row = quad*4 + reg (m89/m91).
  const float* be = bias + e * NDIM;
  const size_t row0 = (size_t)m_blk * 256 + (size_t)wm * 128 + q * 4;
  const int col0 = n_blk * 256 + wn * 64 + lo16;
#pragma unroll
  for (int j = 0; j < 4; ++j) {
    const int col = col0 + j * 16;
    const float bv = be[col];
#pragma unroll
    for (int i = 0; i < 8; ++i) {
#pragma unroll
      for (int r = 0; r < 4; ++r) {
        const size_t row = row0 + i * 16 + r;
        float v = acc[i][j][r] + bv;
        if (GELU) v = gelu_fast(v);
        // Non-temporal: h/out written once, not re-read soon on this XCD.
        __builtin_nontemporal_store((OutT)v, &Out[row * (size_t)NDIM + col]);
      }
    }
  }
#undef STAGE_A
#undef STAGE_B
}

extern "C" void kernel_launch(void* const* d_in, const int* in_sizes, int n_in,
                              void* d_out, int out_size, void* d_ws, size_t ws_size,
                              hipStream_t stream) {
  const float* x  = (const float*)d_in[0];   // [4,8192,1024]
  const float* w1 = (const float*)d_in[1];   // [8,4096,1024]
  const float* b1 = (const float*)d_in[2];   // [8,4096]
  const float* w2 = (const float*)d_in[3];   // [8,1024,4096]
  const float* b2 = (const float*)d_in[4];   // [8,1024]
  float* out = (float*)d_out;                // [4,8192,1024] fp32
  char* ws = (char*)d_ws;

  // ws layout (448 MiB): xb 64MiB | w1b 64MiB | w2b 64MiB | hb 256MiB
  bf16* xb  = (bf16*)(ws + 0);
  bf16* w1b = (bf16*)(ws + 67108864ull);
  bf16* w2b = (bf16*)(ws + 134217728ull);
  bf16* hb  = (bf16*)(ws + 201326592ull);

  const int n4 = 33554432 / 4;
  dim3 cgrid(n4 / 256), cblk(256);
  cvt_f32_to_bf16<<<cgrid, cblk, 0, stream>>>((const float4*)x,  (bf16x4*)xb,  n4);
  cvt_f32_to_bf16<<<cgrid, cblk, 0, stream>>>((const float4*)w1, (bf16x4*)w1b, n4);
  cvt_f32_to_bf16<<<cgrid, cblk, 0, stream>>>((const float4*)w2, (bf16x4*)w2b, n4);

  // GEMM1: h = gelu(x @ w1^T + b1), K=1024, N=4096, bf16 out. 2048 blocks.
  gemm256_8ph<1024, 4096, true, bf16>
      <<<dim3(2048), dim3(512), 0, stream>>>(xb, w1b, b1, hb);
  // GEMM2: y = h @ w2^T + b2, K=4096, N=1024, fp32 out. 512 blocks.
  gemm256_8ph<4096, 1024, false, float>
      <<<dim3(512), dim3(512), 0, stream>>>(hb, w2b, b2, out);
}